// Round 1
// 1095.353 us; speedup vs baseline: 1.7130x; 1.7130x over previous
//
#include <hip/hip_runtime.h>
#include <hip/hip_fp16.h>
#include <cstdint>
#include <cstddef>

#define BB  256
#define TT  2048
#define KIN 182
#define HH  64
#define G3  192   // 3*H
#define CH  16    // timesteps per chunk (MFMA M)
#define NC  (TT/CH)   // 128 chunks

typedef _Float16 half8 __attribute__((ext_vector_type(8)));
typedef _Float16 h2v   __attribute__((ext_vector_type(2)));
typedef float    f32x4 __attribute__((ext_vector_type(4)));
typedef float    v2f   __attribute__((ext_vector_type(2)));

static __device__ __forceinline__ float dot2(h2v a, h2v b, float c) {
#if __has_builtin(__builtin_amdgcn_fdot2)
    return __builtin_amdgcn_fdot2(a, b, c, false);
#else
    return c + (float)a[0] * (float)b[0] + (float)a[1] * (float)b[1];
#endif
}

// ---------------------------------------------------------------------------
// Fused GRU: one block per batch, 2 waves.
//   wave 1 (producer): IG chunk c+1 = x[16 rows] @ W_ih^T + bias via 72 MFMA,
//                      parked fp32 in LDS double buffer. A-frags direct from
//                      global x (b64 pairs, 8B-aligned), B-frags from
//                      L2-resident W_ih, bias folded into MFMA C-init.
//   wave 0 (consumer): wave-synchronous scan. W_hh resident as fp16 half2
//                      (96 VGPRs), matvec via v_dot2_f32_f16, h broadcast
//                      through 128B of LDS (8 uniform b128 reads/step).
// ---------------------------------------------------------------------------
__global__ __launch_bounds__(128, 1) void gru_fused(
        const float* __restrict__ x,
        const float* __restrict__ wih,
        const float* __restrict__ whh,
        const float* __restrict__ bias,
        const float* __restrict__ bias_n,
        const float* __restrict__ wout,
        const float* __restrict__ outb,
        float* __restrict__ out)
{
    __shared__ float igb[2][CH][G3];              // 24.6 KB, fp32 IG park
    __shared__ __align__(16) _Float16 hs[HH];     // h broadcast, fp16

    const int tid  = threadIdx.x;
    const int lane = tid & 63;
    const int wid  = tid >> 6;
    const int b    = blockIdx.x;

    if (wid == 1) {
        // ------------------------- producer wave --------------------------
        const int col = lane & 15;    // m (timestep row) for A, n for B/D
        const int kq  = lane >> 4;    // 0..3
        float bv[12];
#pragma unroll
        for (int nt = 0; nt < 12; ++nt) bv[nt] = bias[nt * 16 + col];

        const float* xb = x + (size_t)b * TT * KIN;

        auto produce = [&](int c, int buf) {
            const float* xr = xb + (size_t)(c * CH + col) * KIN;
            // A fragments: x[c*16+col][k], k = kf*32 + kq*8 + j  (pad k>=182 -> 0)
            v2f xa[6][4];
#pragma unroll
            for (int kf = 0; kf < 6; ++kf)
#pragma unroll
                for (int j = 0; j < 4; ++j) {
                    int k = kf * 32 + kq * 8 + 2 * j;
                    v2f z2 = {0.f, 0.f};
                    xa[kf][j] = (k <= 180) ? *(const v2f*)(xr + k) : z2;
                }
            half8 af[6];
#pragma unroll
            for (int kf = 0; kf < 6; ++kf) {
                half8 t;
#pragma unroll
                for (int j = 0; j < 4; ++j) {
                    t[2 * j]     = (_Float16)xa[kf][j].x;
                    t[2 * j + 1] = (_Float16)xa[kf][j].y;
                }
                af[kf] = t;
            }
#pragma unroll
            for (int nt = 0; nt < 12; ++nt) {
                const float* wrow = wih + (size_t)(nt * 16 + col) * KIN + kq * 8;
                v2f bb[6][4];
#pragma unroll
                for (int kf = 0; kf < 6; ++kf)
#pragma unroll
                    for (int j = 0; j < 4; ++j) {
                        int k = kf * 32 + kq * 8 + 2 * j;
                        v2f z2 = {0.f, 0.f};
                        bb[kf][j] = (k <= 180) ? *(const v2f*)(wrow + kf * 32 + 2 * j) : z2;
                    }
                // bias folded into C-init (same value for every row of the tile)
                f32x4 cacc = {bv[nt], bv[nt], bv[nt], bv[nt]};
#pragma unroll
                for (int kf = 0; kf < 6; ++kf) {
                    half8 bt;
#pragma unroll
                    for (int j = 0; j < 4; ++j) {
                        bt[2 * j]     = (_Float16)bb[kf][j].x;
                        bt[2 * j + 1] = (_Float16)bb[kf][j].y;
                    }
                    cacc = __builtin_amdgcn_mfma_f32_16x16x32_f16(af[kf], bt, cacc, 0, 0, 0);
                }
                // D layout: row = kq*4 + r (timestep), col = nt*16 + col (gate)
                float* dst = &igb[buf][kq * 4][nt * 16 + col];
#pragma unroll
                for (int r = 0; r < 4; ++r) dst[r * G3] = cacc[r];
            }
        };

        produce(0, 0);
        __syncthreads();                          // chunk 0 ready
        for (int c = 0; c < NC; ++c) {
            if (c + 1 < NC) produce(c + 1, (c + 1) & 1);
            __syncthreads();                      // chunk c consumed / c+1 ready
        }
        // producer exits; no barriers remain for the consumer
    } else {
        // ------------------------- consumer wave --------------------------
        const int i = lane;                       // owns h_i and gate rows i
        // W_hh rows i, 64+i, 128+i as fp16 half2: 96 VGPRs total
        h2v wr[32], wz[32], wn[32];
        {
            const v2f* pr = (const v2f*)(whh + (size_t)(0 * HH + i) * HH);
            const v2f* pz = (const v2f*)(whh + (size_t)(1 * HH + i) * HH);
            const v2f* pn = (const v2f*)(whh + (size_t)(2 * HH + i) * HH);
#pragma unroll
            for (int k = 0; k < 32; ++k) {
                v2f a = pr[k], c2 = pz[k], d2 = pn[k];
                h2v t;
                t[0] = (_Float16)a.x;  t[1] = (_Float16)a.y;  wr[k] = t;
                t[0] = (_Float16)c2.x; t[1] = (_Float16)c2.y; wz[k] = t;
                t[0] = (_Float16)d2.x; t[1] = (_Float16)d2.y; wn[k] = t;
            }
        }
        const float bn = bias_n[i];
        float h = 0.f;
        hs[i] = (_Float16)0.f;

        __syncthreads();                          // chunk 0 ready

        for (int c = 0; c < NC; ++c) {
            const float* igrow = &igb[c & 1][0][0];
#pragma unroll 4
            for (int lt = 0; lt < CH; ++lt) {
                const float* p = igrow + lt * G3;
                float pr_ = p[i], pz_ = p[64 + i], pn_ = p[128 + i];
                float r0 = 0.f, r1 = 0.f, z0 = 0.f, z1 = 0.f, n0 = 0.f, n1 = 0.f;
                const half8* hp = (const half8*)hs;
#pragma unroll
                for (int q = 0; q < 8; ++q) {     // 96 v_dot2_f32_f16, 6 chains
                    half8 hv = hp[q];
                    h2v h0 = __builtin_shufflevector(hv, hv, 0, 1);
                    h2v h1 = __builtin_shufflevector(hv, hv, 2, 3);
                    h2v h2_ = __builtin_shufflevector(hv, hv, 4, 5);
                    h2v h3 = __builtin_shufflevector(hv, hv, 6, 7);
                    r0 = dot2(wr[4 * q + 0], h0, r0);
                    z0 = dot2(wz[4 * q + 0], h0, z0);
                    n0 = dot2(wn[4 * q + 0], h0, n0);
                    r1 = dot2(wr[4 * q + 1], h1, r1);
                    z1 = dot2(wz[4 * q + 1], h1, z1);
                    n1 = dot2(wn[4 * q + 1], h1, n1);
                    r0 = dot2(wr[4 * q + 2], h2_, r0);
                    z0 = dot2(wz[4 * q + 2], h2_, z0);
                    n0 = dot2(wn[4 * q + 2], h2_, n0);
                    r1 = dot2(wr[4 * q + 3], h3, r1);
                    z1 = dot2(wz[4 * q + 3], h3, z1);
                    n1 = dot2(wn[4 * q + 3], h3, n1);
                }
                float sr = r0 + r1, sz = z0 + z1, sn = n0 + n1;
                float r  = 1.f / (1.f + __expf(-(pr_ + sr)));
                float z  = 1.f / (1.f + __expf(-(pz_ + sz)));
                float e  = __expf(2.f * (pn_ + r * (sn + bn)));   // tanh via exp
                float nn = 1.f - 2.f / (e + 1.f);
                h = nn + z * (h - nn);
                __builtin_amdgcn_wave_barrier();  // all hs reads issued before write
                hs[i] = (_Float16)h;
                __builtin_amdgcn_wave_barrier();  // write ordered before next reads
            }
            __syncthreads();                      // hand buffer back to producer
        }

        // readout: sigmoid(h . w_out^T + out_bias), butterfly reduce
        float s0 = wout[i] * h, s1 = wout[HH + i] * h;
#pragma unroll
        for (int off = 32; off > 0; off >>= 1) {
            s0 += __shfl_down(s0, off);
            s1 += __shfl_down(s1, off);
        }
        if (i == 0) {
            out[2 * b]     = 1.f / (1.f + __expf(-(s0 + outb[0])));
            out[2 * b + 1] = 1.f / (1.f + __expf(-(s1 + outb[1])));
        }
    }
}

extern "C" void kernel_launch(void* const* d_in, const int* in_sizes, int n_in,
                              void* d_out, int out_size, void* d_ws, size_t ws_size,
                              hipStream_t stream) {
    const float* x     = (const float*)d_in[0];
    const float* wih   = (const float*)d_in[1];
    const float* whh   = (const float*)d_in[2];
    const float* bias  = (const float*)d_in[3];
    const float* biasn = (const float*)d_in[4];
    const float* wout  = (const float*)d_in[5];
    const float* outb  = (const float*)d_in[6];
    float* out = (float*)d_out;
    (void)d_ws; (void)ws_size;   // no workspace needed anymore

    gru_fused<<<BB, 128, 0, stream>>>(x, wih, whh, bias, biasn, wout, outb, out);
}